// Round 9
// baseline (369.751 us; speedup 1.0000x reference)
//
#include <hip/hip_runtime.h>
#include <math.h>

#define DM   1024
#define DS   64
#define BATCH 8
#define SEQ  2048
#define CL   32          // chunk length
#define NC   64          // number of chunks (SEQ/CL)
#define NBLK 512         // mega-kernel grid; 2 blocks/CU -> all co-resident

typedef __bf16 bf16x8 __attribute__((ext_vector_type(8)));
typedef float  f32x4  __attribute__((ext_vector_type(4)));

#if __has_builtin(__builtin_amdgcn_exp2f)
#define EXP2(v) __builtin_amdgcn_exp2f(v)
#else
#define EXP2(v) __expf(0.69314718056f * (v))
#endif

// LDS-only barrier (intra-block): orders LDS traffic without draining vmcnt.
#define LBAR() do {                                                           \
    asm volatile("s_waitcnt lgkmcnt(0)" ::: "memory");                        \
    __builtin_amdgcn_s_barrier();                                             \
    asm volatile("" ::: "memory");                                            \
} while (0)

// ---------------------------------------------------------------------------
// Device-scope grid barrier.  Safe because grid == NBLK with resources for
// 4 blocks/CU (LDS) and >=2 blocks/CU (VGPR): all NBLK blocks are resident
// before any can block.  Counters are memset to 0 each launch (captured in
// the same stream/graph), and the ticket formula is monotonic-safe anyway.
// Release: __threadfence before arrive; acquire: AGENT-scope atomic load
// (invalidates L1; per-XCD L2 coherence via the atomic point).  [G16]
// ---------------------------------------------------------------------------
__device__ __forceinline__ void gbar(unsigned* ctr)
{
    __syncthreads();
    if (threadIdx.x == 0) {
        __threadfence();
        unsigned my = __hip_atomic_fetch_add(
            ctr, 1u, __ATOMIC_ACQ_REL, __HIP_MEMORY_SCOPE_AGENT);
        unsigned target = my - (my % NBLK) + NBLK;
        while (__hip_atomic_load(ctr, __ATOMIC_ACQUIRE,
                                 __HIP_MEMORY_SCOPE_AGENT) < target)
            __builtin_amdgcn_s_sleep(2);
        __threadfence();
    }
    __syncthreads();
}

// ---------------------------------------------------------------------------
// Pipelined affine-scan combine (16-j-wide, 256 thr: i=tid>>2, jg=tid&3).
// 1-deep prefetch hides the next record's L2/L3 latency.  (proven)
// ---------------------------------------------------------------------------
__device__ __forceinline__ void scan_range(
    const float* __restrict__ Eb, const float* __restrict__ Db,
    int n0, int n1, int bb_, int i_, int jg_,
    const float* __restrict__ alog, float* __restrict__ h)
{
    if (n0 >= n1) return;
    size_t idx = ((size_t)n0 * BATCH + bb_) * 64 + i_;
    float dsA = Db[idx];
    const float4* ep = (const float4*)(Eb + idx * 64 + jg_ * 16);
    float4 e0 = ep[0], e1 = ep[1], e2 = ep[2], e3 = ep[3];
    for (int n = n0; n < n1; ++n) {
        float dsN = 0.f;
        float4 f0 = make_float4(0.f,0.f,0.f,0.f), f1 = f0, f2 = f0, f3 = f0;
        if (n + 1 < n1) {
            size_t idx2 = ((size_t)(n + 1) * BATCH + bb_) * 64 + i_;
            dsN = Db[idx2];
            const float4* fp = (const float4*)(Eb + idx2 * 64 + jg_ * 16);
            f0 = fp[0]; f1 = fp[1]; f2 = fp[2]; f3 = fp[3];
        }
        float ev[16] = {e0.x,e0.y,e0.z,e0.w, e1.x,e1.y,e1.z,e1.w,
                        e2.x,e2.y,e2.z,e2.w, e3.x,e3.y,e3.z,e3.w};
        #pragma unroll
        for (int k = 0; k < 16; ++k)
            h[k] = EXP2(alog[k] * dsA) * h[k] + ev[k];
        dsA = dsN; e0 = f0; e1 = f1; e2 = f2; e3 = f3;
    }
}

// ---------------------------------------------------------------------------
// MEGA-KERNEL: wconv -> B0 -> GEMM+epilogue+pass1 (round-8 proven) -> B1 ->
// group composites -> B2 -> two-level prefix + replay -> out.
// d/u/ct NEVER touch global: they stay in this block's LDS between P1 and P3
// (s_c unions the dead sA region).  LDS total 34816 B -> 4 blocks/CU cap.
// ---------------------------------------------------------------------------
__global__ __launch_bounds__(256, 2) void mega_kernel(
    const float* __restrict__ x,
    const float* __restrict__ Wd, const float* __restrict__ Wb,
    const float* __restrict__ Wc,
    const float* __restrict__ bd, const float* __restrict__ bb,
    const float* __restrict__ bc, const float* __restrict__ A_log,
    __bf16* __restrict__ Wp,
    float* __restrict__ E, float* __restrict__ Dsum,
    float* __restrict__ Eg, float* __restrict__ Dg,
    unsigned* __restrict__ ctrs,
    float* __restrict__ out)
{
    __shared__ __align__(16) char smem[34816];
    __bf16* sAb = (__bf16*)smem;                 // [4][32*72] = 18432 B
    float*  s_c = (float*)smem;                  // unions sA (dead after GEMM)
    float*  s_d = (float*)(smem + 18432);        // 8 KB
    float*  s_u = (float*)(smem + 26624);        // 8 KB

    const int tid  = threadIdx.x;
    const int row0 = blockIdx.x * 32;

    // ---------------- P0: W pre-convert (grid-stride) ----------------
    for (int idx = blockIdx.x * 256 + tid; idx < 192 * 1024; idx += NBLK * 256) {
        int k = idx & 1023;
        int n = idx >> 10;                       // 0..191
        const float* W = (n < 64) ? Wd : (n < 128 ? Wb : Wc);
        float v = W[(size_t)(n & 63) * DM + k];
        int kt = k >> 5, kk = k & 31;
        Wp[((size_t)kt * 192 + n) * 32 + kk] = (__bf16)v;
    }
    gbar(ctrs + 0);                              // Wp visible to all

    // ---------------- P1: GEMM + epilogue + pass1 (round-8 proven) ----------
    const int lane = tid & 63, wv = tid >> 6;
    const int l15  = lane & 15, quad = lane >> 4;
    const int nbase = wv * 48;

    const int am = tid >> 3;                     // staging row 0..31
    const int ak = tid & 7;                      // 8-float k-group 0..7
    const float* xga = x + (size_t)(row0 + am) * DM + ak * 8;
    const __bf16* wpb = Wp + (nbase + l15) * 32 + quad * 8;

    f32x4 acc[2][3];
    #pragma unroll
    for (int mt = 0; mt < 2; ++mt)
        #pragma unroll
        for (int nt = 0; nt < 3; ++nt)
            acc[mt][nt] = (f32x4){0.f, 0.f, 0.f, 0.f};

    float4 areg[4];
    bf16x8 bA[6], bB[6];

    #define LOADA2(pp) do {                                                   \
        areg[0] = *(const float4*)(xga + (pp) * 128);                         \
        areg[1] = *(const float4*)(xga + (pp) * 128 + 4);                     \
        areg[2] = *(const float4*)(xga + (pp) * 128 + 64);                    \
        areg[3] = *(const float4*)(xga + (pp) * 128 + 68);                    \
    } while (0)
    #define STAGEA2(be, bo) do {                                              \
        bf16x8 h0 = {(__bf16)areg[0].x, (__bf16)areg[0].y,                    \
                     (__bf16)areg[0].z, (__bf16)areg[0].w,                    \
                     (__bf16)areg[1].x, (__bf16)areg[1].y,                    \
                     (__bf16)areg[1].z, (__bf16)areg[1].w};                   \
        *(bf16x8*)&sAb[(be) * 2304 + am * 72 + ak * 8] = h0;                  \
        bf16x8 h1 = {(__bf16)areg[2].x, (__bf16)areg[2].y,                    \
                     (__bf16)areg[2].z, (__bf16)areg[2].w,                    \
                     (__bf16)areg[3].x, (__bf16)areg[3].y,                    \
                     (__bf16)areg[3].z, (__bf16)areg[3].w};                   \
        *(bf16x8*)&sAb[(bo) * 2304 + am * 72 + ak * 8] = h1;                  \
    } while (0)
    #define LOADBF(dst, kb) do {                                              \
        const __bf16* wb_ = wpb + (size_t)(kb) * 12288;                       \
        dst[0] = *(const bf16x8*)(wb_);                                       \
        dst[1] = *(const bf16x8*)(wb_ + 512);                                 \
        dst[2] = *(const bf16x8*)(wb_ + 1024);                                \
        dst[3] = *(const bf16x8*)(wb_ + 6144);                                \
        dst[4] = *(const bf16x8*)(wb_ + 6656);                                \
        dst[5] = *(const bf16x8*)(wb_ + 7168);                                \
    } while (0)
    #define COMPUTE(bi, bfr) do {                                             \
        _Pragma("unroll")                                                     \
        for (int s = 0; s < 2; ++s) {                                         \
            bf16x8 af0 = *(const bf16x8*)                                     \
                &sAb[(bi) * 2304 + (l15) * 72 + s * 32 + quad * 8];           \
            bf16x8 af1 = *(const bf16x8*)                                     \
                &sAb[(bi) * 2304 + (16 + l15) * 72 + s * 32 + quad * 8];      \
            _Pragma("unroll")                                                 \
            for (int nt = 0; nt < 3; ++nt) {                                  \
                acc[0][nt] = __builtin_amdgcn_mfma_f32_16x16x32_bf16(         \
                    af0, bfr[s * 3 + nt], acc[0][nt], 0, 0, 0);               \
                acc[1][nt] = __builtin_amdgcn_mfma_f32_16x16x32_bf16(         \
                    af1, bfr[s * 3 + nt], acc[1][nt], 0, 0, 0);               \
            }                                                                 \
        }                                                                     \
    } while (0)

    LOADA2(0);
    STAGEA2(0, 1);
    LOADA2(1);
    LOADBF(bA, 0);
    LBAR();

    for (int p = 0; p < 8; ++p) {
        const int pe = (p & 1) * 2, po = pe + 1;
        LOADBF(bB, 2 * p + 1);
        COMPUTE(pe, bA);
        if (p < 7) STAGEA2(pe ^ 2, po ^ 2);
        if (p < 6) LOADA2(p + 2);
        if (p < 7) LOADBF(bA, 2 * p + 2);
        COMPUTE(po, bB);
        LBAR();
    }
    #undef LOADA2
    #undef STAGEA2
    #undef LOADBF
    #undef COMPUTE

    // epilogue: bias + activations -> LDS ONLY (s_c overlays dead sA)
    #pragma unroll
    for (int nt = 0; nt < 3; ++nt) {
        int gn  = nbase + nt * 16 + l15;
        int mat = (nbase + nt * 16) >> 6;
        int col = gn & 63;
        float bias = (mat == 0) ? bd[col] : (mat == 1 ? bb[col] : bc[col]);
        #pragma unroll
        for (int mt = 0; mt < 2; ++mt) {
            #pragma unroll
            for (int r = 0; r < 4; ++r) {
                int tl = mt * 16 + quad * 4 + r;     // local t 0..31
                int m  = row0 + tl;
                float v = acc[mt][nt][r] + bias;
                if (mat == 0) {
                    float sp = (v > 20.f) ? v : __logf(1.f + __expf(v));
                    s_d[tl * 64 + col] = sp;
                } else if (mat == 1) {
                    s_u[tl * 64 + col] = v * x[(size_t)m * DM + col];
                } else {
                    s_c[tl * 64 + col] = v;
                }
            }
        }
    }
    LBAR();

    // pass1: local chunk scan from h=0 -> E, Dsum (global, cross-block)
    const int bidx = row0 >> 11;                 // batch
    const int cidx = (row0 >> 5) & 63;           // chunk
    {
        const int si = tid & 63;
        const int sj = tid >> 6;
        float alog1[16];
        const float4* ar = (const float4*)(A_log + si * 64 + sj * 16);
        #pragma unroll
        for (int qq = 0; qq < 4; ++qq) {
            float4 v = ar[qq];
            alog1[4*qq+0] = v.x * 1.44269504f; alog1[4*qq+1] = v.y * 1.44269504f;
            alog1[4*qq+2] = v.z * 1.44269504f; alog1[4*qq+3] = v.w * 1.44269504f;
        }
        float h1[16];
        #pragma unroll
        for (int k = 0; k < 16; ++k) h1[k] = 0.f;
        float dsum = 0.f;
        for (int t = 0; t < CL; ++t) {
            float d = s_d[t * 64 + si];
            dsum += d;
            const float* up = s_u + t * 64 + sj * 16;
            #pragma unroll
            for (int k = 0; k < 16; ++k)
                h1[k] = EXP2(alog1[k] * d) * h1[k] + up[k];
        }
        float* eo = E + (((size_t)cidx * BATCH + bidx) * 64 + si) * 64 + sj * 16;
        #pragma unroll
        for (int qq = 0; qq < 4; ++qq)
            ((float4*)eo)[qq] =
                make_float4(h1[4*qq], h1[4*qq+1], h1[4*qq+2], h1[4*qq+3]);
        if (sj == 0) Dsum[((size_t)cidx * BATCH + bidx) * 64 + si] = dsum;
    }

    gbar(ctrs + 16);                             // E/Dsum visible

    // ---------------- P2: group composites (blocks 0..63) ----------------
    const int i  = tid >> 2;                     // 0..63
    const int jg = tid & 3;                      // 0..3
    float alog[16];
    {
        const float4* ar2 = (const float4*)(A_log + i * 64 + jg * 16);
        #pragma unroll
        for (int qq = 0; qq < 4; ++qq) {
            float4 v = ar2[qq];
            alog[4*qq+0] = v.x * 1.44269504f; alog[4*qq+1] = v.y * 1.44269504f;
            alog[4*qq+2] = v.z * 1.44269504f; alog[4*qq+3] = v.w * 1.44269504f;
        }
    }
    if (blockIdx.x < 64) {
        const int g2 = blockIdx.x >> 3, b2 = blockIdx.x & 7;
        float hg[16];
        #pragma unroll
        for (int k = 0; k < 16; ++k) hg[k] = 0.f;
        scan_range(E, Dsum, g2 * 8, g2 * 8 + 8, b2, i, jg, alog, hg);
        float4* ego = (float4*)(Eg + (((size_t)g2 * BATCH + b2) * 64 + i) * 64
                                   + jg * 16);
        ego[0] = make_float4(hg[0],  hg[1],  hg[2],  hg[3]);
        ego[1] = make_float4(hg[4],  hg[5],  hg[6],  hg[7]);
        ego[2] = make_float4(hg[8],  hg[9],  hg[10], hg[11]);
        ego[3] = make_float4(hg[12], hg[13], hg[14], hg[15]);
        if (jg == 0) {
            float Dacc = 0.f;
            #pragma unroll
            for (int q = 0; q < 8; ++q)
                Dacc += Dsum[((size_t)(g2 * 8 + q) * BATCH + b2) * 64 + i];
            Dg[((size_t)g2 * BATCH + b2) * 64 + i] = Dacc;
        }
    }

    gbar(ctrs + 32);                             // Eg/Dg visible

    // ---------------- P3: two-level prefix + replay (d/u/c from LDS) -------
    {
        float h[16];
        #pragma unroll
        for (int k = 0; k < 16; ++k) h[k] = 0.f;
        const int g = cidx >> 3;
        scan_range(Eg, Dg, 0, g, bidx, i, jg, alog, h);
        scan_range(E, Dsum, g * 8, cidx, bidx, i, jg, alog, h);

        const int t0 = cidx * CL;
        for (int t = 0; t < CL; ++t) {
            float d = s_d[t * 64 + i];
            const float* up  = s_u + t * 64 + jg * 16;
            const float* cp2 = s_c + t * 64 + jg * 16;
            float part = 0.f;
            #pragma unroll
            for (int k = 0; k < 16; ++k) {
                h[k] = EXP2(alog[k] * d) * h[k] + up[k];
                part += cp2[k] * h[k];
            }
            part += __shfl_xor(part, 1);
            part += __shfl_xor(part, 2);
            if (jg == 0)
                out[((size_t)bidx * SEQ + t0 + t) * DS + i] = part;
        }
    }
}

// ---------------------------------------------------------------------------
// Inputs: 0:x 1..6:(cog/beh/env dead) 7:W_delta 8:b_delta 9:W_Bp 10:b_Bp
//         11:W_Cp 12:b_Cp 13:A_log
// ---------------------------------------------------------------------------
extern "C" void kernel_launch(void* const* d_in, const int* in_sizes, int n_in,
                              void* d_out, int out_size, void* d_ws, size_t ws_size,
                              hipStream_t stream)
{
    (void)in_sizes; (void)n_in; (void)out_size; (void)ws_size;
    const float* x     = (const float*)d_in[0];
    const float* Wd    = (const float*)d_in[7];
    const float* bd    = (const float*)d_in[8];
    const float* Wb    = (const float*)d_in[9];
    const float* bb    = (const float*)d_in[10];
    const float* Wc    = (const float*)d_in[11];
    const float* bc    = (const float*)d_in[12];
    const float* A_log = (const float*)d_in[13];
    float* out = (float*)d_out;

    float* ws = (float*)d_ws;
    unsigned* ctrs = (unsigned*)ws;            // 64 uints (3 barriers, 64B apart)
    float* E    = ws + 64;                     // 2,097,152 floats
    float* Dsum = ws + 64 + 2097152;           // 32,768
    float* Eg   = ws + 64 + 2129920;           // 262,144
    float* Dg   = ws + 64 + 2392064;           // 4,096
    __bf16* Wp  = (__bf16*)(ws + 64 + 2396160);// 196,608 bf16

    hipMemsetAsync(ctrs, 0, 256, stream);      // reset barrier counters

    mega_kernel<<<NBLK, 256, 0, stream>>>(
        x, Wd, Wb, Wc, bd, bb, bc, A_log, Wp, E, Dsum, Eg, Dg, ctrs, out);
}

// Round 10
// 169.697 us; speedup vs baseline: 2.1789x; 2.1789x over previous
//
#include <hip/hip_runtime.h>
#include <math.h>

#define DM   1024
#define DS   64
#define BATCH 8
#define SEQ  2048
#define CL   32          // chunk length
#define NC   64          // number of chunks (SEQ/CL)

typedef __bf16 bf16x8 __attribute__((ext_vector_type(8)));
typedef float  f32x4  __attribute__((ext_vector_type(4)));

#if __has_builtin(__builtin_amdgcn_exp2f)
#define EXP2(v) __builtin_amdgcn_exp2f(v)
#else
#define EXP2(v) __expf(0.69314718056f * (v))
#endif

// LDS-only barrier (intra-block): orders LDS traffic without draining vmcnt.
#define LBAR() do {                                                           \
    asm volatile("s_waitcnt lgkmcnt(0)" ::: "memory");                        \
    __builtin_amdgcn_s_barrier();                                             \
    asm volatile("" ::: "memory");                                            \
} while (0)

// ---------------------------------------------------------------------------
// Kernel W: pre-convert W_delta|W_Bp|W_Cp into packed bf16, K-tiled:
// Wp[(kt*192 + n)*32 + kk], k = kt*32+kk.  (proven)
// ---------------------------------------------------------------------------
__global__ __launch_bounds__(256) void wconv_kernel(
    const float* __restrict__ Wd, const float* __restrict__ Wb,
    const float* __restrict__ Wc, __bf16* __restrict__ Wp)
{
    int idx = blockIdx.x * 256 + threadIdx.x;   // n*1024 + k
    int k  = idx & 1023;
    int n  = idx >> 10;                          // 0..191
    const float* W = (n < 64) ? Wd : (n < 128 ? Wb : Wc);
    float v = W[(size_t)(n & 63) * DM + k];
    int kt = k >> 5, kk = k & 31;
    Wp[((size_t)kt * 192 + n) * 32 + kk] = (__bf16)v;
}

// ---------------------------------------------------------------------------
// Kernel A+B fused: projection + pass1 local scan.  Round-8 structure
// (best measured: 43.5-45.4us), pass1 reads vectorized + unrolled.
// Direct-B from L2-resident Wp; 4-buffer sA pair staging; LDS-only barriers.
// LDS: 4 x 4.5 KB sA + 8 KB s_d + 8 KB s_u = 34 KB.
// MFMA layouts (m89/m91): A/B frag [k=quad*8+j][m|n=l15]; D: col=l15,
// row=quad*4+reg.
// ---------------------------------------------------------------------------
__global__ __launch_bounds__(256, 2) void projp1_full(
    const float* __restrict__ x, const __bf16* __restrict__ Wp,
    const float* __restrict__ bd, const float* __restrict__ bb,
    const float* __restrict__ bc, const float* __restrict__ A_log,
    float* __restrict__ delta_g, float* __restrict__ u_g,
    float* __restrict__ ct_g,
    float* __restrict__ E, float* __restrict__ Dsum)
{
    __shared__ __bf16 sA[4][32 * 72];            // 4 x 4.5 KB
    __shared__ float  s_d[CL * 64];              // 8 KB
    __shared__ float  s_u[CL * 64];              // 8 KB

    const int tid  = threadIdx.x;
    const int row0 = blockIdx.x * 32;

    const int lane = tid & 63, wv = tid >> 6;
    const int l15  = lane & 15, quad = lane >> 4;
    const int nbase = wv * 48;                   // wave's N window

    const int am = tid >> 3;                     // staging row 0..31
    const int ak = tid & 7;                      // 8-float k-group 0..7
    const float* xga = x + (size_t)(row0 + am) * DM + ak * 8;

    // per-lane B base inside a K-block: row (nbase+l15), k-offset quad*8
    const __bf16* wpb = Wp + (nbase + l15) * 32 + quad * 8;

    f32x4 acc[2][3];
    #pragma unroll
    for (int mt = 0; mt < 2; ++mt)
        #pragma unroll
        for (int nt = 0; nt < 3; ++nt)
            acc[mt][nt] = (f32x4){0.f, 0.f, 0.f, 0.f};

    float4 areg[4];                              // x for one K-block PAIR
    bf16x8 bA[6], bB[6];                         // B frags, named

    #define LOADA2(pp) do {                                                   \
        areg[0] = *(const float4*)(xga + (pp) * 128);                         \
        areg[1] = *(const float4*)(xga + (pp) * 128 + 4);                     \
        areg[2] = *(const float4*)(xga + (pp) * 128 + 64);                    \
        areg[3] = *(const float4*)(xga + (pp) * 128 + 68);                    \
    } while (0)
    #define STAGEA2(be, bo) do {                                              \
        bf16x8 h0 = {(__bf16)areg[0].x, (__bf16)areg[0].y,                    \
                     (__bf16)areg[0].z, (__bf16)areg[0].w,                    \
                     (__bf16)areg[1].x, (__bf16)areg[1].y,                    \
                     (__bf16)areg[1].z, (__bf16)areg[1].w};                   \
        *(bf16x8*)&sA[be][am * 72 + ak * 8] = h0;                             \
        bf16x8 h1 = {(__bf16)areg[2].x, (__bf16)areg[2].y,                    \
                     (__bf16)areg[2].z, (__bf16)areg[2].w,                    \
                     (__bf16)areg[3].x, (__bf16)areg[3].y,                    \
                     (__bf16)areg[3].z, (__bf16)areg[3].w};                   \
        *(bf16x8*)&sA[bo][am * 72 + ak * 8] = h1;                             \
    } while (0)
    #define LOADBF(dst, kb) do {                                              \
        const __bf16* wb_ = wpb + (size_t)(kb) * 12288;                       \
        dst[0] = *(const bf16x8*)(wb_);                                       \
        dst[1] = *(const bf16x8*)(wb_ + 512);                                 \
        dst[2] = *(const bf16x8*)(wb_ + 1024);                                \
        dst[3] = *(const bf16x8*)(wb_ + 6144);                                \
        dst[4] = *(const bf16x8*)(wb_ + 6656);                                \
        dst[5] = *(const bf16x8*)(wb_ + 7168);                                \
    } while (0)
    #define COMPUTE(bi, bfr) do {                                             \
        _Pragma("unroll")                                                     \
        for (int s = 0; s < 2; ++s) {                                         \
            bf16x8 af0 = *(const bf16x8*)                                     \
                &sA[bi][(l15) * 72 + s * 32 + quad * 8];                      \
            bf16x8 af1 = *(const bf16x8*)                                     \
                &sA[bi][(16 + l15) * 72 + s * 32 + quad * 8];                 \
            _Pragma("unroll")                                                 \
            for (int nt = 0; nt < 3; ++nt) {                                  \
                acc[0][nt] = __builtin_amdgcn_mfma_f32_16x16x32_bf16(         \
                    af0, bfr[s * 3 + nt], acc[0][nt], 0, 0, 0);               \
                acc[1][nt] = __builtin_amdgcn_mfma_f32_16x16x32_bf16(         \
                    af1, bfr[s * 3 + nt], acc[1][nt], 0, 0, 0);               \
            }                                                                 \
        }                                                                     \
    } while (0)

    // prologue: pair0 staged (bufs 0,1), pair1 in regs, B frags for kb0
    LOADA2(0);
    STAGEA2(0, 1);
    LOADA2(1);
    LOADBF(bA, 0);
    LBAR();

    for (int p = 0; p < 8; ++p) {
        const int pe = (p & 1) * 2, po = pe + 1;     // LDS buf indices
        LOADBF(bB, 2 * p + 1);                        // B odd, used this iter
        COMPUTE(pe, bA);                              // 12 MFMA, kb = 2p
        if (p < 7) STAGEA2(pe ^ 2, po ^ 2);           // stage pair p+1
        if (p < 6) LOADA2(p + 2);                     // x pair p+2, iter ahead
        if (p < 7) LOADBF(bA, 2 * p + 2);             // B next even
        COMPUTE(po, bB);                              // 12 MFMA, kb = 2p+1
        LBAR();                                       // LDS-only barrier
    }
    #undef LOADA2
    #undef STAGEA2
    #undef LOADBF
    #undef COMPUTE

    // epilogue: bias + activations; store global AND stage delta/u in LDS
    #pragma unroll
    for (int nt = 0; nt < 3; ++nt) {
        int gn  = nbase + nt * 16 + l15;         // 0..191
        int mat = (nbase + nt * 16) >> 6;        // wave-uniform per nt
        int col = gn & 63;
        float bias = (mat == 0) ? bd[col] : (mat == 1 ? bb[col] : bc[col]);
        #pragma unroll
        for (int mt = 0; mt < 2; ++mt) {
            #pragma unroll
            for (int r = 0; r < 4; ++r) {
                int tl = mt * 16 + quad * 4 + r; // local t 0..31
                int m  = row0 + tl;
                float v = acc[mt][nt][r] + bias;
                if (mat == 0) {
                    float sp = (v > 20.f) ? v : __logf(1.f + __expf(v));
                    delta_g[(size_t)m * DS + col] = sp;
                    s_d[tl * 64 + col] = sp;
                } else if (mat == 1) {
                    float uu = v * x[(size_t)m * DM + col];
                    u_g[(size_t)m * DS + col] = uu;
                    s_u[tl * 64 + col] = uu;
                } else {
                    ct_g[(size_t)m * DS + col] = v;
                }
            }
        }
    }
    LBAR();                                      // s_d/s_u handoff (LDS only)

    // ---- fused pass1: local chunk scan from h=0 (float4 + unrolled) ----
    const int bidx = row0 >> 11;                 // batch  (row0/2048)
    const int cidx = (row0 >> 5) & 63;           // chunk  ((row0/32)%64)
    const int si = tid & 63;
    const int sj = tid >> 6;

    float alog[16];
    {
        const float4* ar = (const float4*)(A_log + si * 64 + sj * 16);
        #pragma unroll
        for (int qq = 0; qq < 4; ++qq) {
            float4 v = ar[qq];
            alog[4*qq+0] = v.x * 1.44269504f; alog[4*qq+1] = v.y * 1.44269504f;
            alog[4*qq+2] = v.z * 1.44269504f; alog[4*qq+3] = v.w * 1.44269504f;
        }
    }

    float h[16];
    #pragma unroll
    for (int k = 0; k < 16; ++k) h[k] = 0.f;
    float dsum = 0.f;

    #pragma unroll 4
    for (int t = 0; t < CL; ++t) {
        float d = s_d[t * 64 + si];
        dsum += d;
        const float4* up4 = (const float4*)(s_u + t * 64 + sj * 16);
        float4 u0 = up4[0], u1 = up4[1], u2 = up4[2], u3 = up4[3];
        float uv[16] = {u0.x,u0.y,u0.z,u0.w, u1.x,u1.y,u1.z,u1.w,
                        u2.x,u2.y,u2.z,u2.w, u3.x,u3.y,u3.z,u3.w};
        #pragma unroll
        for (int k = 0; k < 16; ++k)
            h[k] = EXP2(alog[k] * d) * h[k] + uv[k];
    }

    float* eo = E + (((size_t)cidx * BATCH + bidx) * 64 + si) * 64 + sj * 16;
    #pragma unroll
    for (int qq = 0; qq < 4; ++qq)
        ((float4*)eo)[qq] = make_float4(h[4*qq], h[4*qq+1], h[4*qq+2], h[4*qq+3]);
    if (sj == 0) Dsum[((size_t)cidx * BATCH + bidx) * 64 + si] = dsum;
}

// ---------------------------------------------------------------------------
// Pipelined affine-scan combine, 8-j-wide, TWO-DEEP record prefetch: two
// (Dsum, E) records in flight so each combine's ~400-600cy L2/L3 latency is
// covered by two predecessors' compute + issue windows.
// ---------------------------------------------------------------------------
__device__ __forceinline__ void scan_range8(
    const float* __restrict__ Eb, const float* __restrict__ Db,
    int n0, int n1, int bb_, int i_, int jg_,
    const float* __restrict__ alog, float* __restrict__ h)
{
    if (n0 >= n1) return;
    size_t idx0 = ((size_t)n0 * BATCH + bb_) * 64 + i_;
    float dsA = Db[idx0];
    const float4* ep0 = (const float4*)(Eb + idx0 * 64 + jg_ * 8);
    float4 a0 = ep0[0], a1 = ep0[1];

    float dsB = 0.f;
    float4 b0 = make_float4(0.f,0.f,0.f,0.f), b1 = b0;
    if (n0 + 1 < n1) {
        size_t idx1 = ((size_t)(n0 + 1) * BATCH + bb_) * 64 + i_;
        dsB = Db[idx1];
        const float4* ep1 = (const float4*)(Eb + idx1 * 64 + jg_ * 8);
        b0 = ep1[0]; b1 = ep1[1];
    }

    for (int n = n0; n < n1; ++n) {
        float dsC = 0.f;
        float4 c0 = make_float4(0.f,0.f,0.f,0.f), c1 = c0;
        if (n + 2 < n1) {
            size_t idx2 = ((size_t)(n + 2) * BATCH + bb_) * 64 + i_;
            dsC = Db[idx2];
            const float4* ep2 = (const float4*)(Eb + idx2 * 64 + jg_ * 8);
            c0 = ep2[0]; c1 = ep2[1];
        }
        float ev[8] = {a0.x,a0.y,a0.z,a0.w, a1.x,a1.y,a1.z,a1.w};
        #pragma unroll
        for (int k = 0; k < 8; ++k)
            h[k] = EXP2(alog[k] * dsA) * h[k] + ev[k];
        dsA = dsB; a0 = b0; a1 = b1;
        dsB = dsC; b0 = c0; b1 = c1;
    }
}

// ---------------------------------------------------------------------------
// Kernel G: group composites, 512 threads (i = tid>>3, jg = tid&7).
// Block (g2,b2) folds chunks 8*g2..8*g2+7 into (Eg, Dg).
// ---------------------------------------------------------------------------
__global__ __launch_bounds__(512) void group_kernel(
    const float* __restrict__ E, const float* __restrict__ Dsum,
    const float* __restrict__ A_log,
    float* __restrict__ Eg, float* __restrict__ Dg)
{
    const int g2 = blockIdx.x >> 3, b2 = blockIdx.x & 7;
    const int tid = threadIdx.x;
    const int i  = tid >> 3;                          // 0..63
    const int jg = tid & 7;                           // 0..7

    float alog[8];
    {
        const float4* ar = (const float4*)(A_log + i * 64 + jg * 8);
        float4 v0 = ar[0], v1 = ar[1];
        alog[0] = v0.x * 1.44269504f; alog[1] = v0.y * 1.44269504f;
        alog[2] = v0.z * 1.44269504f; alog[3] = v0.w * 1.44269504f;
        alog[4] = v1.x * 1.44269504f; alog[5] = v1.y * 1.44269504f;
        alog[6] = v1.z * 1.44269504f; alog[7] = v1.w * 1.44269504f;
    }

    float hg[8];
    #pragma unroll
    for (int k = 0; k < 8; ++k) hg[k] = 0.f;
    scan_range8(E, Dsum, g2 * 8, g2 * 8 + 8, b2, i, jg, alog, hg);

    float4* ego = (float4*)(Eg + (((size_t)g2 * BATCH + b2) * 64 + i) * 64 + jg * 8);
    ego[0] = make_float4(hg[0], hg[1], hg[2], hg[3]);
    ego[1] = make_float4(hg[4], hg[5], hg[6], hg[7]);
    if (jg == 0) {
        float Dacc = 0.f;
        #pragma unroll
        for (int q = 0; q < 8; ++q)
            Dacc += Dsum[((size_t)(g2 * 8 + q) * BATCH + b2) * 64 + i];
        Dg[((size_t)g2 * BATCH + b2) * 64 + i] = Dacc;
    }
}

// ---------------------------------------------------------------------------
// Kernel C+D fused, 512 threads: i = tid>>3 (0..63), jg = tid&7 (0..7),
// 8 j's per thread.  Prefix via 2-deep-prefetch scan; replay with float4
// LDS reads + 4x unroll (batches independent LDS reads per lgkmcnt window).
// ---------------------------------------------------------------------------
__global__ __launch_bounds__(512) void pass23_kernel(
    const float* __restrict__ delta_g, const float* __restrict__ u_g,
    const float* __restrict__ ct_g, const float* __restrict__ A_log,
    const float* __restrict__ E, const float* __restrict__ Dsum,
    const float* __restrict__ Eg, const float* __restrict__ Dg,
    float* __restrict__ out)
{
    __shared__ float s_d[CL * 64];
    __shared__ float s_u[CL * 64];
    __shared__ float s_c[CL * 64];

    const int c = blockIdx.x, b = blockIdx.y, tid = threadIdx.x;
    const int t0 = c * CL;

    // stage d/u/c: 2048 floats each = 512 float4 = exactly 1 per thread
    {
        const float4* dg = (const float4*)(delta_g + ((size_t)b * SEQ + t0) * DS);
        const float4* ug = (const float4*)(u_g     + ((size_t)b * SEQ + t0) * DS);
        const float4* cg = (const float4*)(ct_g    + ((size_t)b * SEQ + t0) * DS);
        ((float4*)s_d)[tid] = dg[tid];
        ((float4*)s_u)[tid] = ug[tid];
        ((float4*)s_c)[tid] = cg[tid];
    }

    const int i  = tid >> 3;                          // 0..63
    const int jg = tid & 7;                           // 0..7

    float alog[8];
    {
        const float4* ar = (const float4*)(A_log + i * 64 + jg * 8);
        float4 v0 = ar[0], v1 = ar[1];
        alog[0] = v0.x * 1.44269504f; alog[1] = v0.y * 1.44269504f;
        alog[2] = v0.z * 1.44269504f; alog[3] = v0.w * 1.44269504f;
        alog[4] = v1.x * 1.44269504f; alog[5] = v1.y * 1.44269504f;
        alog[6] = v1.z * 1.44269504f; alog[7] = v1.w * 1.44269504f;
    }

    // ---- two-level prefix: groups 0..g-1, then chunks 8g..c-1 ----
    float h[8];
    #pragma unroll
    for (int k = 0; k < 8; ++k) h[k] = 0.f;
    const int g = c >> 3;
    scan_range8(Eg, Dg, 0, g, b, i, jg, alog, h);
    scan_range8(E, Dsum, g * 8, c, b, i, jg, alog, h);
    __syncthreads();

    // ---- replay + output ----
    #pragma unroll 4
    for (int t = 0; t < CL; ++t) {
        float d = s_d[t * 64 + i];
        const float4* up4 = (const float4*)(s_u + t * 64 + jg * 8);
        const float4* cp4 = (const float4*)(s_c + t * 64 + jg * 8);
        float4 u0 = up4[0], u1 = up4[1];
        float4 c0 = cp4[0], c1 = cp4[1];
        float uv[8] = {u0.x,u0.y,u0.z,u0.w, u1.x,u1.y,u1.z,u1.w};
        float cv[8] = {c0.x,c0.y,c0.z,c0.w, c1.x,c1.y,c1.z,c1.w};
        float part = 0.f;
        #pragma unroll
        for (int k = 0; k < 8; ++k) {
            h[k] = EXP2(alog[k] * d) * h[k] + uv[k];
            part += cv[k] * h[k];
        }
        part += __shfl_xor(part, 1);
        part += __shfl_xor(part, 2);
        part += __shfl_xor(part, 4);
        if (jg == 0)
            out[((size_t)b * SEQ + t0 + t) * DS + i] = part;
    }
}

// ---------------------------------------------------------------------------
// Inputs: 0:x 1..6:(cog/beh/env dead) 7:W_delta 8:b_delta 9:W_Bp 10:b_Bp
//         11:W_Cp 12:b_Cp 13:A_log
// ---------------------------------------------------------------------------
extern "C" void kernel_launch(void* const* d_in, const int* in_sizes, int n_in,
                              void* d_out, int out_size, void* d_ws, size_t ws_size,
                              hipStream_t stream)
{
    (void)in_sizes; (void)n_in; (void)out_size; (void)ws_size;
    const float* x     = (const float*)d_in[0];
    const float* Wd    = (const float*)d_in[7];
    const float* bd    = (const float*)d_in[8];
    const float* Wb    = (const float*)d_in[9];
    const float* bb    = (const float*)d_in[10];
    const float* Wc    = (const float*)d_in[11];
    const float* bc    = (const float*)d_in[12];
    const float* A_log = (const float*)d_in[13];
    float* out = (float*)d_out;

    float* ws = (float*)d_ws;
    float* delta_g = ws;                       // 1,048,576 floats
    float* u_g     = ws + 1 * 1048576;         // 1,048,576
    float* ct_g    = ws + 2 * 1048576;         // 1,048,576
    float* E       = ws + 3 * 1048576;         // 2,097,152
    float* Dsum    = ws + 5242880;             // 32,768
    float* Eg      = ws + 5275648;             // 262,144
    float* Dg      = ws + 5537792;             // 4,096
    __bf16* Wp     = (__bf16*)(ws + 5541888);  // 196,608 bf16

    wconv_kernel<<<768, 256, 0, stream>>>(Wd, Wb, Wc, Wp);
    projp1_full<<<512, 256, 0, stream>>>(
        x, Wp, bd, bb, bc, A_log, delta_g, u_g, ct_g, E, Dsum);
    group_kernel<<<64, 512, 0, stream>>>(E, Dsum, A_log, Eg, Dg);
    pass23_kernel<<<dim3(NC, BATCH), 512, 0, stream>>>(
        delta_g, u_g, ct_g, A_log, E, Dsum, Eg, Dg, out);
}